// Round 10
// baseline (561.642 us; speedup 1.0000x reference)
//
#include <hip/hip_runtime.h>
#include <hip/hip_bf16.h>
#include <math.h>

typedef __attribute__((ext_vector_type(8))) short short8;   // 8 x bf16 (4 VGPRs)
typedef __attribute__((ext_vector_type(4))) float floatx4;  // MFMA C/D frag

static __device__ __forceinline__ unsigned short f2bf(float f) {
    unsigned int u = __float_as_uint(f);
    unsigned int r = (u + 0x7fffu + ((u >> 16) & 1u)) >> 16;   // RNE
    return (unsigned short)r;
}

// packed fp32x2 -> bf16x2 (RNE), single VALU inst (no builtin on gfx950)
static __device__ __forceinline__ unsigned int pk_bf16(float lo, float hi) {
    unsigned int r;
    asm("v_cvt_pk_bf16_f32 %0, %1, %2" : "=v"(r) : "v"(lo), "v"(hi));
    return r;
}

// async 16B global -> LDS copy (lds dest = wave-uniform base + lane*16)
static __device__ __forceinline__ void g2l16(const void* g, void* l) {
    __builtin_amdgcn_global_load_lds(
        (const __attribute__((address_space(1))) unsigned int*)g,
        (__attribute__((address_space(3))) unsigned int*)l,
        16, 0, 0);
}

// ---------------------------------------------------------------------------
// Grouped bf16 MFMA GEMM, split-K, fp32 A staged async into LDS.
//   partial[M,N] += A[M,K] @ W[N,K]^T   (atomicAdd into pre-zeroed Cf)
// A staged RAW (fp32) via g2l16 with XOR-swizzled SOURCE (LDS linear, rule
// #21); converted to bf16 via v_cvt_pk_bf16_f32 during fragment load.
// T2 swizzle: fp32 tile [128][8 slots]: src slot (l&7)^(l>>3); read slot
// g^(r&7).  bf16 W tile [128][4 slots]: src slot (c&3)^((c>>3)&3); read
// slot g^((r>>1)&3).
// Tiles: 128x128, 4 waves. XCD-chunked blockid swizzle per group
// (nbb*ksplit and block0 multiples of 8).
// ---------------------------------------------------------------------------
struct GDesc {
    const float*          Af;    // fp32 A
    const unsigned short* W;     // bf16 W, row stride = K
    float*          Cf;          // fp32 partial accum (pre-zeroed)
    int M, N, K;                 // K mult of 32
    int Kreal;                   // A row stride (= K here)
    int nbx;                     // N / 128
    int block0;                  // first flat block id of this group
    int nbb;                     // blocks per k-chunk = nbx * (M/128)
    int ksplit;                  // #k-chunks
};
struct GArgs { GDesc g[3]; int n; };

__global__ __launch_bounds__(256)
void gemm_grouped(GArgs ga)
{
    __shared__ float          As_f[2][4096];   // 2 x 16 KB fp32 A
    __shared__ unsigned short Bs[2][4096];     // 2 x 8 KB bf16 W

    const int bid = blockIdx.x;
    int gi = 0;
    #pragma unroll
    for (int i = 1; i < 3; ++i)
        if (i < ga.n && bid >= ga.g[i].block0) gi = i;
    const GDesc d = ga.g[gi];

    int local = bid - d.block0;
    // XCD-chunked swizzle: consecutive work items land on one XCD
    {
        const int cpx = (d.nbb * d.ksplit) >> 3;
        local = (local & 7) * cpx + (local >> 3);
    }
    int kc = 0;
    int Kc = d.K;
    if (d.ksplit > 1) {
        Kc = d.K / d.ksplit;
        kc = local / d.nbb;
        local -= kc * d.nbb;
    }
    const int kbeg = kc * Kc;
    const int bx = local % d.nbx;
    const int by = local / d.nbx;
    const int row0 = by * 128;
    const int col0 = bx * 128;

    const int tid  = threadIdx.x;
    const int wave = tid >> 6;
    const int lane = tid & 63;
    const int qd   = lane >> 4;
    const int ln   = lane & 15;
    const int wr   = (wave >> 1) * 64;
    const int wc   = (wave & 1) * 64;

    // bf16 W g2l16 chunk mapping: chunk c -> row c>>2, source 16B-slot
    const int c0 = wave * 128 + lane;
    const int c1 = c0 + 64;
    const int r0 = c0 >> 2, k0 = (((c0 & 3) ^ ((c0 >> 3) & 3))) * 8;
    const int r1 = c1 >> 2, k1 = (((c1 & 3) ^ ((c1 >> 3) & 3))) * 8;

    // fp32-A g2l16 mapping: row wave*32+t*8+(l>>3), src col ((l&7)^(l>>3))*4
    const int aro  = wave * 32 + (lane >> 3);  // + t*8
    const int acol = ((lane & 7) ^ (lane >> 3)) * 4;

    const int niter = Kc >> 5;

    floatx4 acc[4][4];
    #pragma unroll
    for (int i = 0; i < 4; ++i)
        #pragma unroll
        for (int j = 0; j < 4; ++j) acc[i][j] = (floatx4){0.f, 0.f, 0.f, 0.f};

    // ---- prologue: stage tile 0 into buffer 0 ----
    g2l16(d.W + (size_t)(col0 + r0) * d.K + kbeg + k0, &Bs[0][(size_t)wave * 1024]);
    g2l16(d.W + (size_t)(col0 + r1) * d.K + kbeg + k1, &Bs[0][(size_t)wave * 1024 + 512]);
    #pragma unroll
    for (int t = 0; t < 4; ++t)
        g2l16(d.Af + (size_t)(row0 + aro + t * 8) * d.Kreal + kbeg + acol,
              &As_f[0][(size_t)(wave * 4 + t) * 256]);
    __syncthreads();

    int cur = 0;
    for (int it = 0; it < niter; ++it) {
        const int nxt = cur ^ 1;
        const bool pf = (it + 1 < niter);

        if (pf) {
            const int kg = kbeg + (it + 1) * 32;
            g2l16(d.W + (size_t)(col0 + r0) * d.K + kg + k0, &Bs[nxt][(size_t)wave * 1024]);
            g2l16(d.W + (size_t)(col0 + r1) * d.K + kg + k1, &Bs[nxt][(size_t)wave * 1024 + 512]);
            #pragma unroll
            for (int t = 0; t < 4; ++t)
                g2l16(d.Af + (size_t)(row0 + aro + t * 8) * d.Kreal + kg + acol,
                      &As_f[nxt][(size_t)(wave * 4 + t) * 256]);
        }

        // ---- compute on current buffer (swizzled reads) ----
        short8 a[4], b[4];
        #pragma unroll
        for (int i = 0; i < 4; ++i) {
            const int row = wr + i * 16 + ln;
            const int sw  = row & 7;
            float4 v0 = *(const float4*)&As_f[cur][row * 32 + ((qd * 2)     ^ sw) * 4];
            float4 v1 = *(const float4*)&As_f[cur][row * 32 + ((qd * 2 + 1) ^ sw) * 4];
            int4 pk = { (int)pk_bf16(v0.x, v0.y), (int)pk_bf16(v0.z, v0.w),
                        (int)pk_bf16(v1.x, v1.y), (int)pk_bf16(v1.z, v1.w) };
            a[i] = *(short8*)&pk;
        }
        #pragma unroll
        for (int j = 0; j < 4; ++j) {
            const int row = wc + j * 16 + ln;
            const int sw  = (row >> 1) & 3;
            b[j] = *(const short8*)&Bs[cur][row * 32 + (qd ^ sw) * 8];
        }
        #pragma unroll
        for (int i = 0; i < 4; ++i)
            #pragma unroll
            for (int j = 0; j < 4; ++j)
                acc[i][j] = __builtin_amdgcn_mfma_f32_16x16x32_bf16(
                                a[i], b[j], acc[i][j], 0, 0, 0);

        __syncthreads();
        cur = nxt;
    }

    // ---- epilogue: atomic fp32 partials; C/D col = lane&15, row = qd*4+r
    #pragma unroll
    for (int j = 0; j < 4; ++j) {
        const int col = col0 + wc + j * 16 + ln;
        #pragma unroll
        for (int i = 0; i < 4; ++i) {
            #pragma unroll
            for (int r = 0; r < 4; ++r) {
                const int row = row0 + wr + i * 16 + qd * 4 + r;
                atomicAdd(&d.Cf[(size_t)row * d.N + col], acc[i][j][r]);
            }
        }
    }
}

// ---------------------------------------------------------------------------
// Prep kernel: stage-1 weights fp32 -> bf16 row-major; stage-2/fc1 weights
// -> packed-transposed u32[k2][Nout] (two bf16 per u32, k ascending);
// zero-fill the stage-1 partial span. One launch.
// ---------------------------------------------------------------------------
struct WSeg { const float* src; void* dst; int Kreal; int Kp; int packed; int nlog; };
struct WArgs { WSeg s[7]; int off[8]; float4* zdst; int zn; };

__global__ __launch_bounds__(256)
void cvt_weights(WArgs wa)
{
    int i = blockIdx.x * 256 + threadIdx.x;
    if (i >= wa.off[7]) {
        int z = i - wa.off[7];
        if (z < wa.zn) wa.zdst[z] = (float4){0.f, 0.f, 0.f, 0.f};
        return;
    }
    int s = 0;
    #pragma unroll
    for (int j = 1; j < 7; ++j) if (i >= wa.off[j]) s = j;
    const WSeg sg = wa.s[s];
    const int li = i - wa.off[s];
    if (sg.packed) {
        // src [Nout][Kreal] -> dst u32[li]: k2 = li>>nlog, c = li&(Nout-1)
        const int c  = li & ((1 << sg.nlog) - 1);
        const int k2 = li >> sg.nlog;
        const int ka = 2 * k2, kb = ka + 1;
        unsigned int lo = (ka < sg.Kreal) ? f2bf(sg.src[(size_t)c * sg.Kreal + ka]) : 0u;
        unsigned int hi = (kb < sg.Kreal) ? f2bf(sg.src[(size_t)c * sg.Kreal + kb]) : 0u;
        ((unsigned int*)sg.dst)[li] = lo | (hi << 16);
        return;
    }
    const int r = li / sg.Kp, c = li - r * sg.Kp;
    ((unsigned short*)sg.dst)[li] =
        (c < sg.Kreal) ? f2bf(sg.src[(size_t)r * sg.Kreal + c]) : (unsigned short)0;
}

// ---------------------------------------------------------------------------
// Mega-fused attention block (one per batch row b):
//   1) BN+ReLU stage-1 partials (sen/obj/bod) -> bf16-packed LDS
//   2) stage-2 row-GEMMs on VALU (packed bf16 weights) -> xs tile
//   3) channel attention (N=10), spatial conv k=7, weighted sum over N
//   4) fc1 (bias+BN+ReLU) -> out[b][256]
// ---------------------------------------------------------------------------
struct AArgs {
    const float *ps, *po, *pb, *bbox, *word;
    const unsigned int *w2s, *w2o, *w2b, *wf;
    const float *g_s, *b_s, *m_s, *v_s;
    const float *g_o, *b_o, *m_o, *v_o;
    const float *g_b, *b_b, *m_b, *v_b;
    const float *Wc1, *Wc2, *Wsa, *bf;
    const float *g_f, *b_f, *m_f, *v_f;
    float* out;
};

static __device__ __forceinline__ unsigned int bnpair(
    const float* src, const float* g, const float* bb,
    const float* m, const float* v, int k2)
{
    float2 a = *(const float2*)(src + 2 * k2);
    float sc0 = g[2 * k2]     * rsqrtf(v[2 * k2]     + 1e-5f);
    float sc1 = g[2 * k2 + 1] * rsqrtf(v[2 * k2 + 1] + 1e-5f);
    float h0 = fmaxf(a.x * sc0 + (bb[2 * k2]     - m[2 * k2]     * sc0), 0.f);
    float h1 = fmaxf(a.y * sc1 + (bb[2 * k2 + 1] - m[2 * k2 + 1] * sc1), 0.f);
    return pk_bf16(h0, h1);
}

__global__ __launch_bounds__(256)
void attn_kernel(AArgs aa)
{
    const int b = blockIdx.x;
    const int tid = threadIdx.x;

    __shared__ float xs[10][688];
    __shared__ float s0[688], s1[688], xr[688];
    __shared__ unsigned int h1p[10][256];     // bf16-packed h1 rows (reused)
    __shared__ float bodv[128];
    __shared__ float avec[10], mvec[10], att[10];
    __shared__ float cw[14], c1[50], c2[50];

    if (tid < 14) cw[tid] = aa.Wsa[tid];
    if (tid < 50) { c1[tid] = aa.Wc1[tid]; c2[tid] = aa.Wc2[tid]; }

    // ---- bbox + word -> xs[.][128..432) (independent of h1) ----
    for (int n = 0; n < 10; ++n) {
        const float* bx = aa.bbox + ((size_t)b * 10 + n) * 4;
        const float* w  = aa.word + ((size_t)b * 10 + n) * 300;
        for (int c = tid; c < 304; c += 256)
            xs[n][128 + c] = (c < 4) ? bx[c] : w[c - 4];
    }

    // ---- sen: BN+ReLU(ps rows) -> h1p; row-GEMM -> xs[.][432..560) ----
    for (int i = tid; i < 2560; i += 256) {
        const int n = i >> 8, k2 = i & 255;
        h1p[n][k2] = bnpair(aa.ps + ((size_t)b * 10 + n) * 512,
                            aa.g_s, aa.b_s, aa.m_s, aa.v_s, k2);
    }
    __syncthreads();
    {
        const int j = tid & 127, n0 = tid >> 7;   // n = n0 + 2t
        float acc[5] = {0.f, 0.f, 0.f, 0.f, 0.f};
        for (int k2 = 0; k2 < 256; ++k2) {
            const unsigned int wv = aa.w2s[k2 * 128 + j];
            const float wlo = __uint_as_float(wv << 16);
            const float whi = __uint_as_float(wv & 0xffff0000u);
            #pragma unroll
            for (int t = 0; t < 5; ++t) {
                const unsigned int hv = h1p[n0 + 2 * t][k2];
                acc[t] += wlo * __uint_as_float(hv << 16)
                        + whi * __uint_as_float(hv & 0xffff0000u);
            }
        }
        __syncthreads();                          // h1p reads done
        #pragma unroll
        for (int t = 0; t < 5; ++t) xs[n0 + 2 * t][432 + j] = acc[t];
    }

    // ---- obj: BN+ReLU(po rows) -> h1p; row-GEMM -> xs[.][0..128) ----
    for (int i = tid; i < 640; i += 256) {
        const int n = i >> 6, k2 = i & 63;
        h1p[n][k2] = bnpair(aa.po + ((size_t)b * 10 + n) * 128,
                            aa.g_o, aa.b_o, aa.m_o, aa.v_o, k2);
    }
    __syncthreads();
    {
        const int j = tid & 127, n0 = tid >> 7;
        float acc[5] = {0.f, 0.f, 0.f, 0.f, 0.f};
        for (int k2 = 0; k2 < 64; ++k2) {
            const unsigned int wv = aa.w2o[k2 * 128 + j];
            const float wlo = __uint_as_float(wv << 16);
            const float whi = __uint_as_float(wv & 0xffff0000u);
            #pragma unroll
            for (int t = 0; t < 5; ++t) {
                const unsigned int hv = h1p[n0 + 2 * t][k2];
                acc[t] += wlo * __uint_as_float(hv << 16)
                        + whi * __uint_as_float(hv & 0xffff0000u);
            }
        }
        __syncthreads();
        #pragma unroll
        for (int t = 0; t < 5; ++t) xs[n0 + 2 * t][j] = acc[t];
    }

    // ---- bod: BN+ReLU(pb row) -> h1p[0]; GEMM -> bodv; bcast xs[.][560..688)
    if (tid < 128)
        h1p[0][tid] = bnpair(aa.pb + (size_t)b * 256,
                             aa.g_b, aa.b_b, aa.m_b, aa.v_b, tid);
    __syncthreads();
    if (tid < 128) {
        float acc = 0.f;
        for (int k2 = 0; k2 < 128; ++k2) {
            const unsigned int wv = aa.w2b[k2 * 128 + tid];
            const unsigned int hv = h1p[0][k2];
            acc += __uint_as_float(wv << 16) * __uint_as_float(hv << 16)
                 + __uint_as_float(wv & 0xffff0000u) * __uint_as_float(hv & 0xffff0000u);
        }
        bodv[tid] = acc;
    }
    __syncthreads();
    for (int i = tid; i < 1280; i += 256) {
        const int n = i >> 7, j = i & 127;
        xs[n][560 + j] = bodv[j];
    }
    __syncthreads();

    // ---- channel attention: wave-parallel per-row mean/max ----
    {
        const int wv = tid >> 6, ln2 = tid & 63;
        for (int n = wv; n < 10; n += 4) {
            float sm = 0.f, mx = -INFINITY;
            for (int c = ln2; c < 688; c += 64) {
                float v = xs[n][c];
                sm += v; mx = fmaxf(mx, v);
            }
            #pragma unroll
            for (int off = 32; off > 0; off >>= 1) {
                sm += __shfl_down(sm, off);
                mx = fmaxf(mx, __shfl_down(mx, off));
            }
            if (ln2 == 0) { avec[n] = sm * (1.f / 688.f); mvec[n] = mx; }
        }
    }
    __syncthreads();

    if (tid == 0) {
        float ha[5], hm[5];
        #pragma unroll
        for (int i = 0; i < 5; ++i) {
            float sa_ = 0.f, sm_ = 0.f;
            #pragma unroll
            for (int j = 0; j < 10; ++j) {
                sa_ += c1[i * 10 + j] * avec[j];
                sm_ += c1[i * 10 + j] * mvec[j];
            }
            ha[i] = fmaxf(sa_, 0.f);
            hm[i] = fmaxf(sm_, 0.f);
        }
        #pragma unroll
        for (int j = 0; j < 10; ++j) {
            float v = 0.f;
            #pragma unroll
            for (int i = 0; i < 5; ++i) v += c2[j * 5 + i] * (ha[i] + hm[i]);
            att[j] = 1.f / (1.f + expf(-v));
        }
    }
    __syncthreads();

    for (int c = tid; c < 688; c += 256) {
        float sm = 0.f, mx = -INFINITY;
        #pragma unroll
        for (int n = 0; n < 10; ++n) {
            float v = xs[n][c] * att[n];
            xs[n][c] = v;
            sm += v; mx = fmaxf(mx, v);
        }
        s0[c] = sm * 0.1f;
        s1[c] = mx;
    }
    __syncthreads();

    for (int c = tid; c < 688; c += 256) {
        float sa = 0.f;
        #pragma unroll
        for (int j = 0; j < 7; ++j) {
            int cc = c + j - 3;
            if (cc >= 0 && cc < 688)
                sa += cw[j] * s0[cc] + cw[7 + j] * s1[cc];
        }
        float sig = 1.f / (1.f + expf(-sa));
        float sm = 0.f;
        #pragma unroll
        for (int n = 0; n < 10; ++n) sm += xs[n][c];
        xr[c] = sm * sig;
    }
    __syncthreads();

    // ---- fused fc1: out[b][tid] = ReLU(BN(dot(xr, Wf[tid]) + bf[tid])) ----
    {
        float acc = 0.f;
        #pragma unroll 4
        for (int k2 = 0; k2 < 344; ++k2) {
            unsigned int w2 = aa.wf[(size_t)k2 * 256 + tid];
            acc += __uint_as_float(w2 << 16)         * xr[2 * k2]
                 + __uint_as_float(w2 & 0xffff0000u) * xr[2 * k2 + 1];
        }
        float sc = aa.g_f[tid] * rsqrtf(aa.v_f[tid] + 1e-5f);
        float sh = aa.b_f[tid] - aa.m_f[tid] * sc;
        aa.out[(size_t)b * 256 + tid] = fmaxf((acc + aa.bf[tid]) * sc + sh, 0.f);
    }
}

// ---------------------------------------------------------------------------
extern "C" void kernel_launch(void* const* d_in, const int* in_sizes, int n_in,
                              void* d_out, int out_size, void* d_ws, size_t ws_size,
                              hipStream_t stream)
{
    const float* f_obj = (const float*)d_in[0];
    const float* bbox  = (const float*)d_in[1];
    const float* word  = (const float*)d_in[2];
    const float* sent  = (const float*)d_in[3];
    const float* body  = (const float*)d_in[4];
    const float* W1_o  = (const float*)d_in[5];
    const float* g_o = (const float*)d_in[6],  *b_o = (const float*)d_in[7];
    const float* m_o = (const float*)d_in[8],  *v_o = (const float*)d_in[9];
    const float* W2_o  = (const float*)d_in[10];
    const float* W1_s  = (const float*)d_in[11];
    const float* g_s = (const float*)d_in[12], *b_s = (const float*)d_in[13];
    const float* m_s = (const float*)d_in[14], *v_s = (const float*)d_in[15];
    const float* W2_s  = (const float*)d_in[16];
    const float* W1_b  = (const float*)d_in[17];
    const float* g_b = (const float*)d_in[18], *b_b = (const float*)d_in[19];
    const float* m_b = (const float*)d_in[20], *v_b = (const float*)d_in[21];
    const float* W2_b  = (const float*)d_in[22];
    const float* Wc1 = (const float*)d_in[23];
    const float* Wc2 = (const float*)d_in[24];
    const float* Wsa = (const float*)d_in[25];
    const float* Wf  = (const float*)d_in[26];
    const float* bf  = (const float*)d_in[27];
    const float* g_f = (const float*)d_in[28], *b_f = (const float*)d_in[29];
    const float* m_f = (const float*)d_in[30], *v_f = (const float*)d_in[31];
    float* out = (float*)d_out;

    // ---- workspace carve (~33.3 MB) ----
    char* p = (char*)d_ws;
    unsigned short* w1s  = (unsigned short*)p; p += 4194304;   // 512*4096 bf16
    unsigned short* w1o  = (unsigned short*)p; p += 262144;    // 128*1024
    unsigned short* w1b  = (unsigned short*)p; p += 1048576;   // 256*2048
    unsigned int*   w2sp = (unsigned int*)p;   p += 131072;    // 256*128 u32
    unsigned int*   w2op = (unsigned int*)p;   p += 32768;     // 64*128 u32
    unsigned int*   w2bp = (unsigned int*)p;   p += 65536;     // 128*128 u32
    unsigned int*   wfpk = (unsigned int*)p;   p += 360448;    // 352*256 u32
    // stage-1 partial span (zero-filled by prep)
    char* zbase = p;
    float* ps = (float*)p; p += 20971520;                      // 10240*512 f32
    float* po = (float*)p; p += 5242880;                       // 10240*128 f32
    float* pb = (float*)p; p += 1048576;                       // 1024*256 f32
    const int zbytes = 27262976;
    if ((size_t)(p - (char*)d_ws) > ws_size) return;

    // ---- 1) weight conversion/packing + zero partials, one launch ----
    WArgs wa;
    wa.s[0] = { W1_s, w1s,  4096, 4096, 0, 0 };
    wa.s[1] = { W1_o, w1o,  1024, 1024, 0, 0 };
    wa.s[2] = { W1_b, w1b,  2048, 2048, 0, 0 };
    wa.s[3] = { W2_s, w2sp,  512, 0,    1, 7 };   // 256 k2 x 128 out
    wa.s[4] = { W2_o, w2op,  128, 0,    1, 7 };   // 64  k2 x 128 out
    wa.s[5] = { W2_b, w2bp,  256, 0,    1, 7 };   // 128 k2 x 128 out
    wa.s[6] = { Wf,   wfpk,  688, 0,    1, 8 };   // 352 k2 x 256 out
    const int wn[7] = { 512*4096, 128*1024, 256*2048, 32768, 8192, 16384, 90112 };
    wa.off[0] = 0;
    for (int i = 0; i < 7; ++i) wa.off[i + 1] = wa.off[i] + wn[i];
    wa.zdst = (float4*)zbase;
    wa.zn   = zbytes / 16;
    cvt_weights<<<(wa.off[7] + wa.zn + 255) / 256, 256, 0, stream>>>(wa);

    // ---- 2) stage-1 grouped GEMM, split-K x2 -> fp32 partials ----
    //      grid: sent 2*320 + obj 2*80 + body 2*16 = 832 blocks
    {
        GArgs ga; ga.n = 3;
        ga.g[0] = { sent,  w1s, ps, 10240, 512, 4096, 4096, 4, 0,   320, 2 };
        ga.g[1] = { f_obj, w1o, po, 10240, 128, 1024, 1024, 1, 640, 80,  2 };
        ga.g[2] = { body,  w1b, pb, 1024,  256, 2048, 2048, 2, 800, 16,  2 };
        gemm_grouped<<<832, 256, 0, stream>>>(ga);
    }

    // ---- 3) mega-fused: BN+stage-2 row-GEMMs + attention + fc1 -> out ----
    {
        AArgs aa;
        aa.ps = ps; aa.po = po; aa.pb = pb; aa.bbox = bbox; aa.word = word;
        aa.w2s = w2sp; aa.w2o = w2op; aa.w2b = w2bp; aa.wf = wfpk;
        aa.g_s = g_s; aa.b_s = b_s; aa.m_s = m_s; aa.v_s = v_s;
        aa.g_o = g_o; aa.b_o = b_o; aa.m_o = m_o; aa.v_o = v_o;
        aa.g_b = g_b; aa.b_b = b_b; aa.m_b = m_b; aa.v_b = v_b;
        aa.Wc1 = Wc1; aa.Wc2 = Wc2; aa.Wsa = Wsa; aa.bf = bf;
        aa.g_f = g_f; aa.b_f = b_f; aa.m_f = m_f; aa.v_f = v_f;
        aa.out = out;
        attn_kernel<<<1024, 256, 0, stream>>>(aa);
    }
}